// Round 1
// baseline (300.227 us; speedup 1.0000x reference)
//
#include <hip/hip_runtime.h>
#include <hip/hip_bf16.h>
#include <math.h>

typedef _Float16 f16;
typedef _Float16 f16x4 __attribute__((ext_vector_type(4)));
typedef float f32x4 __attribute__((ext_vector_type(4)));

#define MIDC 256
#define NHEADS 8
#define HEADC 32
#define HW_ 4096
#define BATCH 8
#define NTOK (BATCH*HW_)   // 32768

// ---------------- converts ----------------
__global__ void k_f32_to_f16(const float* __restrict__ in, f16* __restrict__ out, int n){
    int i = (blockIdx.x*blockDim.x + threadIdx.x)*4;
    if (i < n) {
        float4 v = *reinterpret_cast<const float4*>(in + i);
        f16x4 o = { (f16)v.x, (f16)v.y, (f16)v.z, (f16)v.w };
        *reinterpret_cast<f16x4*>(out + i) = o;
    }
}

// in[R][C] fp32 -> out[C][R] f16   (weights are small; coalesced read, scattered write ok)
__global__ void k_transpose_f16(const float* __restrict__ in, f16* __restrict__ out, int R, int C){
    int idx = blockIdx.x*blockDim.x + threadIdx.x;
    if (idx < R*C) {
        int r = idx / C, c = idx % C;
        out[(size_t)c*R + r] = (f16)in[idx];
    }
}

// ---------------- GEMM: C = A[M,K] * B[K,N], B given transposed Bt[N,K] ----------------
// MODE 0: +bias, scatter into q/k/v [B,H,HW,32] f16
// MODE 1: +bias, exact GELU, -> oh f16 [M,256]
// MODE 2: +bias, +resid fp32, -> of fp32 [M,256]
template<int MODE>
__global__ __launch_bounds__(256) void k_gemm(
    const f16* __restrict__ A, const f16* __restrict__ Bt,
    int M_, int N_, int K_,
    const float* __restrict__ bias,
    f16* __restrict__ oq, f16* __restrict__ ok, f16* __restrict__ ov,
    f16* __restrict__ oh,
    const float* __restrict__ resid, float* __restrict__ of)
{
    __shared__ __attribute__((aligned(16))) f16 As[64][40]; // +8 pad -> 80B stride (16B aligned, 2-way banks)
    __shared__ __attribute__((aligned(16))) f16 Bs[64][40];

    const int tid  = threadIdx.x;
    const int lane = tid & 63, wid = tid >> 6;
    const int m0 = blockIdx.y * 64, n0 = blockIdx.x * 64;
    const int wm = (wid >> 1) * 32, wn = (wid & 1) * 32;
    const int lr = lane & 15, kg = lane >> 4;     // frag row, k-group (0..3)

    f32x4 acc[2][2];
    f32x4 zero = {0.f, 0.f, 0.f, 0.f};
    #pragma unroll
    for (int i=0;i<2;i++)
        #pragma unroll
        for (int j=0;j<2;j++) acc[i][j] = zero;

    const int srow = tid >> 2, sc8 = (tid & 3) << 3;  // staging: 64 rows x 32 cols, 8 f16 per thread
    const f16* aptr = A  + (size_t)(m0 + srow)*K_ + sc8;
    const f16* bptr = Bt + (size_t)(n0 + srow)*K_ + sc8;

    for (int kt = 0; kt < K_; kt += 32) {
        *reinterpret_cast<uint4*>(&As[srow][sc8]) = *reinterpret_cast<const uint4*>(aptr + kt);
        *reinterpret_cast<uint4*>(&Bs[srow][sc8]) = *reinterpret_cast<const uint4*>(bptr + kt);
        __syncthreads();
        f16x4 af[2][2], bf[2][2]; // [k-half][frag]
        #pragma unroll
        for (int kh=0; kh<2; kh++){
            #pragma unroll
            for (int f=0; f<2; f++){
                af[kh][f] = *reinterpret_cast<const f16x4*>(&As[wm + f*16 + lr][kh*16 + kg*4]);
                bf[kh][f] = *reinterpret_cast<const f16x4*>(&Bs[wn + f*16 + lr][kh*16 + kg*4]);
            }
        }
        #pragma unroll
        for (int kh=0; kh<2; kh++)
            #pragma unroll
            for (int fr=0; fr<2; fr++)
                #pragma unroll
                for (int fc=0; fc<2; fc++)
                    acc[fr][fc] = __builtin_amdgcn_mfma_f32_16x16x16f16(af[kh][fr], bf[kh][fc], acc[fr][fc], 0, 0, 0);
        __syncthreads();
    }

    // epilogue: D row = 4*(lane>>4)+reg, col = lane&15
    #pragma unroll
    for (int fr=0; fr<2; fr++)
    #pragma unroll
    for (int fc=0; fc<2; fc++)
    #pragma unroll
    for (int r=0; r<4; r++){
        int gm = m0 + wm + fr*16 + kg*4 + r;
        int gn = n0 + wn + fc*16 + lr;
        float v = acc[fr][fc][r] + bias[gn];
        if (MODE == 0) {
            int h = gn / 96, rr = gn % 96, part = rr >> 5, d = rr & 31;
            int b = gm >> 12, n = gm & 4095;
            size_t idx = ((((size_t)b*NHEADS + h)*HW_) + n)*HEADC + d;
            f16 hv = (f16)v;
            if (part == 0) oq[idx] = hv;
            else if (part == 1) ok[idx] = hv;
            else ov[idx] = hv;
        } else if (MODE == 1) {
            float g = 0.5f * v * (1.0f + erff(v * 0.70710678f));
            oh[(size_t)gm*MIDC + gn] = (f16)g;
        } else {
            of[(size_t)gm*MIDC + gn] = v + resid[(size_t)gm*MIDC + gn];
        }
    }
}

// ---------------- LayerNorm over last dim (32), in place ----------------
__global__ void k_ln(f16* __restrict__ buf, const float* __restrict__ gamma,
                     const float* __restrict__ beta, int nrows){
    int gid = blockIdx.x*blockDim.x + threadIdx.x;
    int row = gid >> 5, col = gid & 31;
    if (row >= nrows) return;
    float v = (float)buf[(size_t)row*32 + col];
    float s = v, s2 = v*v;
    #pragma unroll
    for (int m=16; m>=1; m>>=1){ s += __shfl_xor(s, m); s2 += __shfl_xor(s2, m); }
    float mu  = s * (1.0f/32.0f);
    float var = s2 * (1.0f/32.0f) - mu*mu;
    float rstd = rsqrtf(var + 1e-5f);
    buf[(size_t)row*32 + col] = (f16)((v - mu)*rstd*gamma[col] + beta[col]);
}

// ---------------- kv[d][e] = sum_n k[n][d]*v[n][e], split-K with atomics ----------------
#define KCH 512
__global__ __launch_bounds__(256) void k_kv(const f16* __restrict__ kb, const f16* __restrict__ vb,
                                            float* __restrict__ kv){
    __shared__ __attribute__((aligned(16))) f16 ks[64][32];
    __shared__ __attribute__((aligned(16))) f16 vs[64][32];
    int bh = blockIdx.x, ch = blockIdx.y;
    int tid = threadIdx.x;
    int d = tid >> 3, e0 = (tid & 7) * 4;
    float acc[4] = {0.f,0.f,0.f,0.f};
    const f16* kbase = kb + (size_t)bh*HW_*HEADC + (size_t)ch*KCH*HEADC;
    const f16* vbase = vb + (size_t)bh*HW_*HEADC + (size_t)ch*KCH*HEADC;
    int r = tid >> 2, c8 = (tid & 3) << 3;
    for (int t0 = 0; t0 < KCH; t0 += 64) {
        *reinterpret_cast<uint4*>(&ks[r][c8]) = *reinterpret_cast<const uint4*>(kbase + (size_t)(t0+r)*HEADC + c8);
        *reinterpret_cast<uint4*>(&vs[r][c8]) = *reinterpret_cast<const uint4*>(vbase + (size_t)(t0+r)*HEADC + c8);
        __syncthreads();
        #pragma unroll 8
        for (int tt=0; tt<64; tt++){
            float kk = (float)ks[tt][d];
            #pragma unroll
            for (int j=0;j<4;j++) acc[j] += kk * (float)vs[tt][e0+j];
        }
        __syncthreads();
    }
    float* dst = kv + (size_t)bh*1024 + d*32 + e0;
    #pragma unroll
    for (int j=0;j<4;j++) atomicAdd(dst + j, acc[j]);
}

// ---------------- out = q @ kv / HW + x  -> ret (f16) ----------------
__global__ __launch_bounds__(256) void k_attn(const f16* __restrict__ qb, const float* __restrict__ kv,
                                              const float* __restrict__ x, f16* __restrict__ ret){
    __shared__ float kvs[32][32];
    __shared__ __attribute__((aligned(16))) f16 qs[128][32];
    int bh = blockIdx.x, ch = blockIdx.y;
    int b = bh >> 3, h = bh & 7;
    int tid = threadIdx.x;
    for (int i = tid; i < 1024; i += 256)
        kvs[i>>5][i&31] = kv[(size_t)bh*1024 + i] * (1.0f/4096.0f);
    {
        const f16* qbase = qb + (size_t)bh*HW_*HEADC + (size_t)ch*128*HEADC;
        int r = tid >> 1, c16 = (tid & 1) * 16;
        *reinterpret_cast<uint4*>(&qs[r][c16])   = *reinterpret_cast<const uint4*>(qbase + (size_t)r*HEADC + c16);
        *reinterpret_cast<uint4*>(&qs[r][c16+8]) = *reinterpret_cast<const uint4*>(qbase + (size_t)r*HEADC + c16 + 8);
    }
    __syncthreads();
    int e = tid & 31, t0 = (tid >> 5) * 16;
    #pragma unroll
    for (int tt=0; tt<16; tt++){
        int tok = t0 + tt;
        float a = 0.f;
        #pragma unroll
        for (int dd=0; dd<32; dd++) a += (float)qs[tok][dd] * kvs[dd][e];
        int gtok = ch*128 + tok;
        size_t m = (size_t)b*HW_ + gtok;
        ret[m*MIDC + h*HEADC + e] = (f16)(a + x[m*MIDC + h*HEADC + e]);
    }
}

extern "C" void kernel_launch(void* const* d_in, const int* in_sizes, int n_in,
                              void* d_out, int out_size, void* d_ws, size_t ws_size,
                              hipStream_t stream) {
    const float* x     = (const float*)d_in[0];
    const float* w_qkv = (const float*)d_in[1];
    const float* b_qkv = (const float*)d_in[2];
    const float* kln_g = (const float*)d_in[3];
    const float* kln_b = (const float*)d_in[4];
    const float* vln_g = (const float*)d_in[5];
    const float* vln_b = (const float*)d_in[6];
    const float* w1    = (const float*)d_in[7];
    const float* b1    = (const float*)d_in[8];
    const float* w2    = (const float*)d_in[9];
    const float* b2    = (const float*)d_in[10];
    float* out = (float*)d_out;

    char* ws = (char*)d_ws;
    size_t off = 0;
    auto alloc = [&](size_t bytes) -> void* {
        void* p = ws + off; off += (bytes + 255) & ~255ULL; return p;
    };
    const size_t TOKB = (size_t)NTOK*MIDC*sizeof(f16); // 16 MB
    f16* xb    = (f16*)alloc(TOKB);            // later reused as ret
    f16* wqkvT = (f16*)alloc(768*256*sizeof(f16));
    f16* w1T   = (f16*)alloc(256*256*sizeof(f16));
    f16* w2T   = (f16*)alloc(256*256*sizeof(f16));
    f16* qb    = (f16*)alloc(TOKB);            // later reused as h
    f16* kb    = (f16*)alloc(TOKB);
    f16* vb    = (f16*)alloc(TOKB);
    float* kvbuf = (float*)alloc(64*1024*sizeof(float));
    f16* retb = xb;   // x (f16 copy) dead after GEMM1
    f16* hb   = qb;   // q dead after k_attn

    // 1. converts
    k_f32_to_f16<<<dim3((NTOK*MIDC)/4/256), 256, 0, stream>>>(x, xb, NTOK*MIDC);
    k_transpose_f16<<<dim3((256*768+255)/256), 256, 0, stream>>>(w_qkv, wqkvT, 256, 768);
    k_transpose_f16<<<dim3(256), 256, 0, stream>>>(w1, w1T, 256, 256);
    k_transpose_f16<<<dim3(256), 256, 0, stream>>>(w2, w2T, 256, 256);

    // 2. QKV GEMM + scatter
    k_gemm<0><<<dim3(768/64, NTOK/64), 256, 0, stream>>>(
        xb, wqkvT, NTOK, 768, 256, b_qkv, qb, kb, vb, nullptr, nullptr, nullptr);

    // 3. LayerNorm k, v (in place)
    k_ln<<<dim3((NTOK*NHEADS)/8), 256, 0, stream>>>(kb, kln_g, kln_b, NTOK*NHEADS);
    k_ln<<<dim3((NTOK*NHEADS)/8), 256, 0, stream>>>(vb, vln_g, vln_b, NTOK*NHEADS);

    // 4. kv outer-product reduction (split-K, atomic)
    hipMemsetAsync(kvbuf, 0, 64*1024*sizeof(float), stream);
    k_kv<<<dim3(64, HW_/KCH), 256, 0, stream>>>(kb, vb, kvbuf);

    // 5. out = q@kv + residual
    k_attn<<<dim3(64, HW_/128), 256, 0, stream>>>(qb, kvbuf, x, retb);

    // 6. MLP1 (+GELU)
    k_gemm<1><<<dim3(256/64, NTOK/64), 256, 0, stream>>>(
        retb, w1T, NTOK, 256, 256, b1, nullptr, nullptr, nullptr, hb, nullptr, nullptr);

    // 7. MLP2 (+bias +residual) -> fp32 out
    k_gemm<2><<<dim3(256/64, NTOK/64), 256, 0, stream>>>(
        hb, w2T, NTOK, 256, 256, b2, nullptr, nullptr, nullptr, nullptr, x, out);
}

// Round 3
// 218.367 us; speedup vs baseline: 1.3749x; 1.3749x over previous
//
#include <hip/hip_runtime.h>
#include <hip/hip_bf16.h>
#include <math.h>

typedef _Float16 f16;
typedef _Float16 f16x4 __attribute__((ext_vector_type(4)));
typedef _Float16 f16x8 __attribute__((ext_vector_type(8)));
typedef float f32x4 __attribute__((ext_vector_type(4)));

#define MIDC 256
#define NHEADS 8
#define HEADC 32
#define HW_ 4096
#define BATCH 8
#define NTOK (BATCH*HW_)   // 32768

__device__ __forceinline__ void gload_lds16(const void* g, void* lds){
    __builtin_amdgcn_global_load_lds(
        (const __attribute__((address_space(1))) unsigned int*)g,
        (__attribute__((address_space(3))) unsigned int*)lds, 16, 0, 0);
}

// ---------------- converts ----------------
__global__ void k_f32_to_f16(const float* __restrict__ in, f16* __restrict__ out, int n){
    int i = (blockIdx.x*blockDim.x + threadIdx.x)*4;
    if (i < n) {
        float4 v = *reinterpret_cast<const float4*>(in + i);
        f16x4 o = { (f16)v.x, (f16)v.y, (f16)v.z, (f16)v.w };
        *reinterpret_cast<f16x4*>(out + i) = o;
    }
}

// plain transpose: in[R][C] fp32 -> out[C][R] f16
__global__ void k_transpose_f16(const float* __restrict__ in, f16* __restrict__ out, int R, int C){
    int idx = blockIdx.x*blockDim.x + threadIdx.x;
    if (idx < R*C) {
        int r = idx / C, c = idx % C;
        out[(size_t)c*R + r] = (f16)in[idx];
    }
}

// qkv transpose with column permutation: orig col o = h*96 + p*32 + d  ->  n = p*256 + h*32 + d
__global__ void k_transpose_qkv(const float* __restrict__ in, f16* __restrict__ out){
    int idx = blockIdx.x*blockDim.x + threadIdx.x; // over 256*768
    int r = idx / 768, o = idx % 768;
    int h = o / 96, rr = o % 96, p = rr >> 5, d = o & 31;
    int n = (p << 8) + (h << 5) + d;
    out[(size_t)n*256 + r] = (f16)in[idx];
}

__global__ void k_permute_bias(const float* __restrict__ b, float* __restrict__ pb){
    int n = threadIdx.x; // 768
    int p = n >> 8, h = (n & 255) >> 5, d = n & 31;
    pb[n] = b[h*96 + p*32 + d];
}

// ---------------- GEMM: C = A[M,K] f16 * Bt[N,K] f16, 128x128 tile, BK=32 ----------------
// MODE 0: +bias(permuted), LN on k/v parts, scatter q/k/v [B,H,HW,32] f16
// MODE 1: +bias, exact GELU -> oh f16 [M,256]
// MODE 2: +bias, +resid f32 -> of f32 [M,256]
template<int MODE>
__global__ __launch_bounds__(256) void k_gemm(
    const f16* __restrict__ A, const f16* __restrict__ Bt,
    int K_,
    const float* __restrict__ bias,
    const float* __restrict__ kg_, const float* __restrict__ kb_,
    const float* __restrict__ vg_, const float* __restrict__ vb_,
    f16* __restrict__ oq, f16* __restrict__ ok, f16* __restrict__ ov,
    f16* __restrict__ oh,
    const float* __restrict__ resid, float* __restrict__ of)
{
    __shared__ __attribute__((aligned(16))) f16 As[128][32];
    __shared__ __attribute__((aligned(16))) f16 Bs[128][32];

    const int tid  = threadIdx.x;
    const int lane = tid & 63, wid = tid >> 6;
    const int m0 = blockIdx.y * 128, n0 = blockIdx.x * 128;
    const int wm = (wid >> 1) * 64, wn = (wid & 1) * 64;
    const int lr = lane & 15, kg = lane >> 4;

    f32x4 acc[4][4];
    f32x4 zero = {0.f,0.f,0.f,0.f};
    #pragma unroll
    for (int i=0;i<4;i++)
        #pragma unroll
        for (int j=0;j<4;j++) acc[i][j] = zero;

    const int srow = tid >> 2, scol = (tid & 3) * 8;
    const f16* gA = A  + (size_t)(m0 + srow)*K_ + scol;
    const f16* gB = Bt + (size_t)(n0 + srow)*K_ + scol;
    f16* asf = &As[0][0]; f16* bsf = &Bs[0][0];
    f16* as1 = asf + wid*512; f16* as2 = asf + 2048 + wid*512;
    f16* bs1 = bsf + wid*512; f16* bs2 = bsf + 2048 + wid*512;
    const size_t rstep = (size_t)64*K_;

    for (int kt = 0; kt < K_; kt += 32) {
        gload_lds16(gA + kt,          as1);
        gload_lds16(gA + kt + rstep,  as2);
        gload_lds16(gB + kt,          bs1);
        gload_lds16(gB + kt + rstep,  bs2);
        __syncthreads();
        f16x8 a[4], b[4];
        #pragma unroll
        for (int fr=0; fr<4; fr++) a[fr] = *reinterpret_cast<const f16x8*>(&As[wm + fr*16 + lr][kg*8]);
        #pragma unroll
        for (int fc=0; fc<4; fc++) b[fc] = *reinterpret_cast<const f16x8*>(&Bs[wn + fc*16 + lr][kg*8]);
        #pragma unroll
        for (int fr=0; fr<4; fr++)
            #pragma unroll
            for (int fc=0; fc<4; fc++)
                acc[fr][fc] = __builtin_amdgcn_mfma_f32_16x16x32_f16(a[fr], b[fc], acc[fr][fc], 0, 0, 0);
        __syncthreads();
    }

    // epilogue: D row = (lane>>4)*4 + r, col = lane&15
    if (MODE == 0) {
        int part = n0 >> 8;            // 0=q, 1=k, 2=v
        int nb = (n0 & 255) + wn;      // col base within part for this wave
        float g0=1.f, g1=1.f, be0=0.f, be1=0.f;
        if (part == 1){ g0 = kg_[lr]; g1 = kg_[lr+16]; be0 = kb_[lr]; be1 = kb_[lr+16]; }
        if (part == 2){ g0 = vg_[lr]; g1 = vg_[lr+16]; be0 = vb_[lr]; be1 = vb_[lr+16]; }
        f16* dst = (part == 0) ? oq : (part == 1 ? ok : ov);
        #pragma unroll
        for (int p2=0; p2<2; p2++){
            int colbase = nb + p2*32;
            int h = colbase >> 5;
            float bias0 = bias[n0 + wn + p2*32 + lr];
            float bias1 = bias[n0 + wn + p2*32 + 16 + lr];
            #pragma unroll
            for (int fr=0; fr<4; fr++)
            #pragma unroll
            for (int r=0; r<4; r++){
                float y0 = acc[fr][2*p2  ][r] + bias0;
                float y1 = acc[fr][2*p2+1][r] + bias1;
                int gm = m0 + wm + fr*16 + kg*4 + r;
                int b  = gm >> 12, n = gm & 4095;
                size_t base = (((size_t)(b*NHEADS + h))*HW_ + n)*HEADC;
                if (part == 0) {
                    dst[base + lr]      = (f16)y0;
                    dst[base + 16 + lr] = (f16)y1;
                } else {
                    float s = y0 + y1, s2 = y0*y0 + y1*y1;
                    #pragma unroll
                    for (int m=8; m>=1; m>>=1){ s += __shfl_xor(s, m); s2 += __shfl_xor(s2, m); }
                    float mu  = s * (1.0f/32.0f);
                    float var = s2 * (1.0f/32.0f) - mu*mu;
                    float rs  = rsqrtf(var + 1e-5f);
                    dst[base + lr]      = (f16)((y0 - mu)*rs*g0 + be0);
                    dst[base + 16 + lr] = (f16)((y1 - mu)*rs*g1 + be1);
                }
            }
        }
    } else {
        #pragma unroll
        for (int fr=0; fr<4; fr++)
        #pragma unroll
        for (int fc=0; fc<4; fc++)
        #pragma unroll
        for (int r=0; r<4; r++){
            int gm = m0 + wm + fr*16 + kg*4 + r;
            int gn = n0 + wn + fc*16 + lr;
            float v = acc[fr][fc][r] + bias[gn];
            if (MODE == 1) {
                float g = 0.5f * v * (1.0f + erff(v * 0.70710678f));
                oh[(size_t)gm*MIDC + gn] = (f16)g;
            } else {
                of[(size_t)gm*MIDC + gn] = v + resid[(size_t)gm*MIDC + gn];
            }
        }
    }
}

// ---------------- kv partials: per (bh, chunk of 256 tokens), 4 waves x 64 tokens ----------------
__global__ __launch_bounds__(256) void k_kv(const f16* __restrict__ kb, const f16* __restrict__ vb,
                                            float* __restrict__ kvpart){
    __shared__ __attribute__((aligned(16))) f16 ks[4][64][32];
    __shared__ __attribute__((aligned(16))) f16 vs[4][64][32];
    __shared__ __attribute__((aligned(16))) float red[4][32][32];
    const int bh = blockIdx.x, chunk = blockIdx.y;
    const int tid = threadIdx.x, lane = tid & 63, wid = tid >> 6;
    const int d0 = (lane >> 3) * 4, e0 = (lane & 7) * 4;
    const int tok0 = chunk*256 + wid*64;

    const f16* kg = kb + ((size_t)bh*HW_ + tok0)*HEADC;
    const f16* vg = vb + ((size_t)bh*HW_ + tok0)*HEADC;
    f16* ksw = &ks[wid][0][0]; f16* vsw = &vs[wid][0][0];
    #pragma unroll
    for (int i=0;i<4;i++){
        gload_lds16(kg + (size_t)(i*16 + (lane>>2))*HEADC + (lane&3)*8, ksw + i*512);
        gload_lds16(vg + (size_t)(i*16 + (lane>>2))*HEADC + (lane&3)*8, vsw + i*512);
    }
    __syncthreads();

    f32x4 acc[4];
    #pragma unroll
    for (int i=0;i<4;i++) acc[i] = (f32x4){0.f,0.f,0.f,0.f};
    #pragma unroll 4
    for (int t=0; t<64; t++){
        f16x4 kk = *reinterpret_cast<const f16x4*>(&ks[wid][t][d0]);
        f16x4 vv = *reinterpret_cast<const f16x4*>(&vs[wid][t][e0]);
        f32x4 vf = { (float)vv[0], (float)vv[1], (float)vv[2], (float)vv[3] };
        #pragma unroll
        for (int i=0;i<4;i++) acc[i] += (float)kk[i] * vf;
    }
    __syncthreads();
    #pragma unroll
    for (int i=0;i<4;i++) *reinterpret_cast<f32x4*>(&red[wid][d0+i][e0]) = acc[i];
    __syncthreads();
    // block reduce 4 waves -> kvpart[bh*16+chunk][1024]
    int de0 = tid * 4;
    const float* rf = &red[0][0][0];
    f32x4 s = *reinterpret_cast<const f32x4*>(rf + de0);
    #pragma unroll
    for (int w=1; w<4; w++) s += *reinterpret_cast<const f32x4*>(rf + w*1024 + de0);
    *reinterpret_cast<f32x4*>(kvpart + ((size_t)bh*16 + chunk)*1024 + de0) = s;
}

// ---------------- reduce partials -> kvT f16 [bh][e][d], scaled 1/HW ----------------
__global__ void k_kvred(const float* __restrict__ kvpart, f16* __restrict__ kvT){
    int gid = blockIdx.x*blockDim.x + threadIdx.x; // 65536
    int bh = gid >> 10, de = gid & 1023;
    int d = de >> 5, e = de & 31;
    float s = 0.f;
    #pragma unroll
    for (int p=0; p<16; p++) s += kvpart[((size_t)bh*16 + p)*1024 + de];
    kvT[((size_t)bh << 10) + (e << 5) + d] = (f16)(s * (1.0f/4096.0f));
}

// ---------------- attn: ret = q @ kvT^T + x, MFMA, 128 tokens x 32 e per block ----------------
__global__ __launch_bounds__(256) void k_attn(const f16* __restrict__ qb, const f16* __restrict__ kvT,
                                              const float* __restrict__ x, f16* __restrict__ ret){
    const int bh = blockIdx.x, chunk = blockIdx.y;
    const int b = bh >> 3, h = bh & 7;
    const int tid = threadIdx.x, lane = tid & 63, wid = tid >> 6;
    const int lr = lane & 15, kg = lane >> 4;
    const int row0 = chunk*128 + wid*32;

    f32x4 acc[2][2];
    #pragma unroll
    for (int i=0;i<2;i++)
        #pragma unroll
        for (int j=0;j<2;j++) acc[i][j] = (f32x4){0.f,0.f,0.f,0.f};

    f16x8 a[2], bb[2];
    #pragma unroll
    for (int fr=0; fr<2; fr++)
        a[fr] = *reinterpret_cast<const f16x8*>(qb + ((size_t)bh*HW_ + row0 + fr*16 + lr)*HEADC + kg*8);
    #pragma unroll
    for (int fc=0; fc<2; fc++)
        bb[fc] = *reinterpret_cast<const f16x8*>(kvT + ((size_t)bh << 10) + (size_t)(fc*16 + lr)*32 + kg*8);
    #pragma unroll
    for (int fr=0; fr<2; fr++)
        #pragma unroll
        for (int fc=0; fc<2; fc++)
            acc[fr][fc] = __builtin_amdgcn_mfma_f32_16x16x32_f16(a[fr], bb[fc], acc[fr][fc], 0, 0, 0);

    #pragma unroll
    for (int fr=0; fr<2; fr++)
    #pragma unroll
    for (int fc=0; fc<2; fc++)
    #pragma unroll
    for (int r=0; r<4; r++){
        int n = row0 + fr*16 + kg*4 + r;
        int e = fc*16 + lr;
        size_t xi = ((size_t)b*HW_ + n)*MIDC + h*HEADC + e;
        ret[xi] = (f16)(acc[fr][fc][r] + x[xi]);
    }
}

extern "C" void kernel_launch(void* const* d_in, const int* in_sizes, int n_in,
                              void* d_out, int out_size, void* d_ws, size_t ws_size,
                              hipStream_t stream) {
    const float* x     = (const float*)d_in[0];
    const float* w_qkv = (const float*)d_in[1];
    const float* b_qkv = (const float*)d_in[2];
    const float* kln_g = (const float*)d_in[3];
    const float* kln_b = (const float*)d_in[4];
    const float* vln_g = (const float*)d_in[5];
    const float* vln_b = (const float*)d_in[6];
    const float* w1    = (const float*)d_in[7];
    const float* b1    = (const float*)d_in[8];
    const float* w2    = (const float*)d_in[9];
    const float* b2    = (const float*)d_in[10];
    float* out = (float*)d_out;

    char* ws = (char*)d_ws;
    size_t off = 0;
    auto alloc = [&](size_t bytes) -> void* {
        void* p = ws + off; off += (bytes + 255) & ~255ULL; return p;
    };
    const size_t TOKB = (size_t)NTOK*MIDC*sizeof(f16); // 16.78 MB
    f16* xb    = (f16*)alloc(TOKB);               // reused as ret
    f16* wqkvT = (f16*)alloc(768*256*sizeof(f16));
    f16* w1T   = (f16*)alloc(256*256*sizeof(f16));
    f16* w2T   = (f16*)alloc(256*256*sizeof(f16));
    float* pb  = (float*)alloc(768*sizeof(float));
    f16* qb    = (f16*)alloc(TOKB);               // reused as h
    f16* kb    = (f16*)alloc(TOKB);
    f16* vb    = (f16*)alloc(TOKB);
    float* kvpart = (float*)alloc((size_t)64*16*1024*sizeof(float)); // 4 MB
    f16* kvT   = (f16*)alloc((size_t)64*1024*sizeof(f16));
    f16* retb = xb;
    f16* hb   = qb;

    // 1. converts / weight prep
    k_f32_to_f16<<<dim3((NTOK*MIDC)/4/256), 256, 0, stream>>>(x, xb, NTOK*MIDC);
    k_transpose_qkv<<<dim3((256*768)/256), 256, 0, stream>>>(w_qkv, wqkvT);
    k_permute_bias<<<dim3(1), 768, 0, stream>>>(b_qkv, pb);
    k_transpose_f16<<<dim3(256), 256, 0, stream>>>(w1, w1T, 256, 256);
    k_transpose_f16<<<dim3(256), 256, 0, stream>>>(w2, w2T, 256, 256);

    // 2. QKV GEMM + bias + LN(k,v) + scatter
    k_gemm<0><<<dim3(768/128, NTOK/128), 256, 0, stream>>>(
        xb, wqkvT, 256, pb, kln_g, kln_b, vln_g, vln_b,
        qb, kb, vb, nullptr, nullptr, nullptr);

    // 3. kv partials + reduce (-> kvT, pre-scaled, transposed)
    k_kv<<<dim3(64, HW_/256), 256, 0, stream>>>(kb, vb, kvpart);
    k_kvred<<<dim3(65536/256), 256, 0, stream>>>(kvpart, kvT);

    // 4. attn + residual -> ret f16
    k_attn<<<dim3(64, HW_/128), 256, 0, stream>>>(qb, kvT, x, retb);

    // 5. MLP1 (+GELU)
    k_gemm<1><<<dim3(256/128, NTOK/128), 256, 0, stream>>>(
        retb, w1T, 256, b1, nullptr, nullptr, nullptr, nullptr,
        nullptr, nullptr, nullptr, hb, nullptr, nullptr);

    // 6. MLP2 (+bias +residual) -> f32 out
    k_gemm<2><<<dim3(256/128, NTOK/128), 256, 0, stream>>>(
        hb, w2T, 256, b2, nullptr, nullptr, nullptr, nullptr,
        nullptr, nullptr, nullptr, nullptr, x, out);
}

// Round 4
// 211.794 us; speedup vs baseline: 1.4175x; 1.0310x over previous
//
#include <hip/hip_runtime.h>
#include <hip/hip_bf16.h>
#include <math.h>

typedef _Float16 f16;
typedef _Float16 f16x4 __attribute__((ext_vector_type(4)));
typedef _Float16 f16x8 __attribute__((ext_vector_type(8)));
typedef float f32x4 __attribute__((ext_vector_type(4)));

#define MIDC 256
#define NHEADS 8
#define HEADC 32
#define HW_ 4096
#define BATCH 8
#define NTOK (BATCH*HW_)   // 32768

__device__ __forceinline__ void gload_lds16(const void* g, void* lds){
    __builtin_amdgcn_global_load_lds(
        (const __attribute__((address_space(1))) unsigned int*)g,
        (__attribute__((address_space(3))) unsigned int*)lds, 16, 0, 0);
}

// ---------------- x f32 -> f16 ----------------
__global__ void k_f32_to_f16(const float* __restrict__ in, f16* __restrict__ out, int n){
    int i = (blockIdx.x*blockDim.x + threadIdx.x)*4;
    if (i < n) {
        float4 v = *reinterpret_cast<const float4*>(in + i);
        f16x4 o = { (f16)v.x, (f16)v.y, (f16)v.z, (f16)v.w };
        *reinterpret_cast<f16x4*>(out + i) = o;
    }
}

// ---------------- merged weight prep ----------------
// wqkv transpose+permute, w1T, w2T, permuted bias
__global__ void k_prep(const float* __restrict__ wqkv, const float* __restrict__ w1,
                       const float* __restrict__ w2, const float* __restrict__ bq,
                       f16* __restrict__ wqkvT, f16* __restrict__ w1T,
                       f16* __restrict__ w2T, float* __restrict__ pb){
    int idx = blockIdx.x*blockDim.x + threadIdx.x;
    if (idx < 196608){                       // wqkv [256][768] -> [768p][256]
        int r = idx / 768, o = idx % 768;
        int h = o / 96, rr = o % 96, p = rr >> 5, d = o & 31;
        int n = (p << 8) + (h << 5) + d;
        wqkvT[(size_t)n*256 + r] = (f16)wqkv[idx];
    } else if (idx < 262144){                // w1 [256][256] -> T
        int i = idx - 196608; int r = i >> 8, c = i & 255;
        w1T[(size_t)c*256 + r] = (f16)w1[i];
    } else if (idx < 327680){                // w2
        int i = idx - 262144; int r = i >> 8, c = i & 255;
        w2T[(size_t)c*256 + r] = (f16)w2[i];
    } else if (idx < 328448){                // bias permute
        int n = idx - 327680;
        int p = n >> 8, h = (n & 255) >> 5, d = n & 31;
        pb[n] = bq[h*96 + p*32 + d];
    }
}

// ---------------- GEMM: C = A[M,256] f16 * Bt[N,256] f16, 128x128 tile, BK=32, 2-phase ----------------
// MODE 0: +bias(permuted), LN on k/v heads, coalesced scatter q/k/v [B,H,HW,32] f16
// MODE 1: +bias, exact GELU -> oh f16 [M,256]
// MODE 2: +bias, +resid f16 -> of f32 [M,256]
template<int MODE>
__global__ __launch_bounds__(256) void k_gemm(
    const f16* __restrict__ A, const f16* __restrict__ Bt,
    const float* __restrict__ bias,
    const float* __restrict__ kg_, const float* __restrict__ kb_,
    const float* __restrict__ vg_, const float* __restrict__ vb_,
    f16* __restrict__ oq, f16* __restrict__ ok, f16* __restrict__ ov,
    f16* __restrict__ oh,
    const f16* __restrict__ residh, float* __restrict__ of)
{
    constexpr int K = 256;
    __shared__ __attribute__((aligned(16))) char smem[(MODE==2) ? 32768 : 50176];
    // buf0: A 0..8K, B 8K..16K ; buf1: A 16K..24K, B 24K..32K ; Cs overlaps buf1 (16K..50K)
    f16* const AsB[2] = { (f16*)(smem),        (f16*)(smem+16384) };
    f16* const BsB[2] = { (f16*)(smem+8192),   (f16*)(smem+24576) };

    const int tid  = threadIdx.x;
    const int lane = tid & 63, wid = tid >> 6;
    const int m0 = blockIdx.y * 128, n0 = blockIdx.x * 128;
    const int wm = (wid >> 1) * 64, wn = (wid & 1) * 64;
    const int lr = lane & 15, kg = lane >> 4;

    f32x4 acc[4][4];
    #pragma unroll
    for (int i=0;i<4;i++)
        #pragma unroll
        for (int j=0;j<4;j++) acc[i][j] = (f32x4){0.f,0.f,0.f,0.f};

    const int srow = tid >> 2, scol = (tid & 3) * 8;
    const f16* gA = A  + (size_t)(m0 + srow)*K + scol;
    const f16* gB = Bt + (size_t)(n0 + srow)*K + scol;
    const size_t rstep = (size_t)64*K;

    auto STAGE = [&](int b, int kt){
        f16* ab = AsB[b] + wid*512;
        f16* bb = BsB[b] + wid*512;
        gload_lds16(gA + kt,          ab);
        gload_lds16(gA + kt + rstep,  ab + 2048);
        gload_lds16(gB + kt,          bb);
        gload_lds16(gB + kt + rstep,  bb + 2048);
    };

    STAGE(1, 0);                 // tile 0 -> buf1
    __syncthreads();             // drains vmcnt(0)

    #pragma unroll
    for (int t = 0; t < 8; ++t){
        const f16* Ac = (t & 1) ? AsB[0] : AsB[1];   // t even -> buf1, t odd -> buf0
        const f16* Bc = (t & 1) ? BsB[0] : BsB[1];
        if (t < 7) STAGE((t & 1) ? 1 : 0, (t+1)*32); // next tile into other buf
        f16x8 a[4], b[4];
        #pragma unroll
        for (int fr=0; fr<4; fr++) a[fr] = *reinterpret_cast<const f16x8*>(Ac + (wm + fr*16 + lr)*32 + kg*8);
        #pragma unroll
        for (int fc=0; fc<4; fc++) b[fc] = *reinterpret_cast<const f16x8*>(Bc + (wn + fc*16 + lr)*32 + kg*8);
        #pragma unroll
        for (int fr=0; fr<4; fr++)
            #pragma unroll
            for (int fc=0; fc<4; fc++)
                acc[fr][fc] = __builtin_amdgcn_mfma_f32_16x16x32_f16(a[fr], b[fc], acc[fr][fc], 0, 0, 0);
        __syncthreads();         // waits this iter's STAGE (vmcnt0) + releases bufs
    }

    if constexpr (MODE != 2){
        // -------- write acc -> Cs[128][132] f16 (bias [+gelu]) --------
        f16* Cs = (f16*)(smem + 16384);
        float bv[4];
        #pragma unroll
        for (int fc=0; fc<4; fc++) bv[fc] = bias[n0 + wn + fc*16 + lr];
        #pragma unroll
        for (int fr=0; fr<4; fr++)
        #pragma unroll
        for (int fc=0; fc<4; fc++)
        #pragma unroll
        for (int r=0; r<4; r++){
            float v = acc[fr][fc][r] + bv[fc];
            if constexpr (MODE == 1) v = 0.5f * v * (1.0f + erff(v * 0.70710678f));
            Cs[(wm + fr*16 + kg*4 + r)*132 + (wn + fc*16 + lr)] = (f16)v;
        }
        __syncthreads();
        // -------- read phase: one (row, 32-col chunk) per thread, x2 --------
        #pragma unroll
        for (int i=0;i<2;i++){
            int c = tid + i*256;
            int row = c >> 2, hc = c & 3;
            const f16* src = Cs + row*132 + hc*32;
            f16x8 d0 = *reinterpret_cast<const f16x8*>(src);
            f16x8 d1 = *reinterpret_cast<const f16x8*>(src + 8);
            f16x8 d2 = *reinterpret_cast<const f16x8*>(src + 16);
            f16x8 d3 = *reinterpret_cast<const f16x8*>(src + 24);
            if constexpr (MODE == 0){
                int col0 = n0 + hc*32;
                int part = col0 >> 8;            // block-uniform
                int h = (col0 & 255) >> 5;
                int gm = m0 + row, b = gm >> 12, n = gm & 4095;
                f16* dst = (part==0 ? oq : (part==1 ? ok : ov))
                         + ((size_t)(b*NHEADS + h)*HW_ + n)*HEADC;
                if (part == 0){
                    *reinterpret_cast<f16x8*>(dst)      = d0;
                    *reinterpret_cast<f16x8*>(dst + 8)  = d1;
                    *reinterpret_cast<f16x8*>(dst + 16) = d2;
                    *reinterpret_cast<f16x8*>(dst + 24) = d3;
                } else {
                    float vals[32];
                    #pragma unroll
                    for (int j=0;j<8;j++){
                        vals[j]    = (float)d0[j];
                        vals[8+j]  = (float)d1[j];
                        vals[16+j] = (float)d2[j];
                        vals[24+j] = (float)d3[j];
                    }
                    float s = 0.f, s2 = 0.f;
                    #pragma unroll
                    for (int j=0;j<32;j++){ s += vals[j]; s2 = fmaf(vals[j], vals[j], s2); }
                    float mu  = s * (1.0f/32.0f);
                    float var = s2 * (1.0f/32.0f) - mu*mu;
                    float rs  = rsqrtf(var + 1e-5f);
                    const float* gp = (part==1) ? kg_ : vg_;
                    const float* bp = (part==1) ? kb_ : vb_;
                    f16x8 o0, o1, o2, o3;
                    #pragma unroll
                    for (int j=0;j<8;j++){
                        o0[j] = (f16)((vals[j]    - mu)*rs*gp[j]    + bp[j]);
                        o1[j] = (f16)((vals[8+j]  - mu)*rs*gp[8+j]  + bp[8+j]);
                        o2[j] = (f16)((vals[16+j] - mu)*rs*gp[16+j] + bp[16+j]);
                        o3[j] = (f16)((vals[24+j] - mu)*rs*gp[24+j] + bp[24+j]);
                    }
                    *reinterpret_cast<f16x8*>(dst)      = o0;
                    *reinterpret_cast<f16x8*>(dst + 8)  = o1;
                    *reinterpret_cast<f16x8*>(dst + 16) = o2;
                    *reinterpret_cast<f16x8*>(dst + 24) = o3;
                }
            } else { // MODE 1
                f16* dst = oh + (size_t)(m0 + row)*MIDC + n0 + hc*32;
                *reinterpret_cast<f16x8*>(dst)      = d0;
                *reinterpret_cast<f16x8*>(dst + 8)  = d1;
                *reinterpret_cast<f16x8*>(dst + 16) = d2;
                *reinterpret_cast<f16x8*>(dst + 24) = d3;
            }
        }
    } else {
        // -------- MODE 2: direct f32 stores + f16 residual --------
        #pragma unroll
        for (int fr=0; fr<4; fr++)
        #pragma unroll
        for (int fc=0; fc<4; fc++)
        #pragma unroll
        for (int r=0; r<4; r++){
            int gm = m0 + wm + fr*16 + kg*4 + r;
            int gn = n0 + wn + fc*16 + lr;
            size_t xi = (size_t)gm*MIDC + gn;
            of[xi] = acc[fr][fc][r] + bias[gn] + (float)residh[xi];
        }
    }
}

// ---------------- kv partials: per (bh, chunk of 256 tokens), 4 waves x 64 tokens ----------------
__global__ __launch_bounds__(256) void k_kv(const f16* __restrict__ kb, const f16* __restrict__ vb,
                                            float* __restrict__ kvpart){
    __shared__ __attribute__((aligned(16))) f16 ks[4][64][32];
    __shared__ __attribute__((aligned(16))) f16 vs[4][64][32];
    __shared__ __attribute__((aligned(16))) float red[4][32][32];
    const int bh = blockIdx.x, chunk = blockIdx.y;
    const int tid = threadIdx.x, lane = tid & 63, wid = tid >> 6;
    const int d0 = (lane >> 3) * 4, e0 = (lane & 7) * 4;
    const int tok0 = chunk*256 + wid*64;

    const f16* kg = kb + ((size_t)bh*HW_ + tok0)*HEADC;
    const f16* vg = vb + ((size_t)bh*HW_ + tok0)*HEADC;
    f16* ksw = &ks[wid][0][0]; f16* vsw = &vs[wid][0][0];
    #pragma unroll
    for (int i=0;i<4;i++){
        gload_lds16(kg + (size_t)(i*16 + (lane>>2))*HEADC + (lane&3)*8, ksw + i*512);
        gload_lds16(vg + (size_t)(i*16 + (lane>>2))*HEADC + (lane&3)*8, vsw + i*512);
    }
    __syncthreads();

    f32x4 acc[4];
    #pragma unroll
    for (int i=0;i<4;i++) acc[i] = (f32x4){0.f,0.f,0.f,0.f};
    #pragma unroll 4
    for (int t=0; t<64; t++){
        f16x4 kk = *reinterpret_cast<const f16x4*>(&ks[wid][t][d0]);
        f16x4 vv = *reinterpret_cast<const f16x4*>(&vs[wid][t][e0]);
        f32x4 vf = { (float)vv[0], (float)vv[1], (float)vv[2], (float)vv[3] };
        #pragma unroll
        for (int i=0;i<4;i++) acc[i] += (float)kk[i] * vf;
    }
    __syncthreads();
    #pragma unroll
    for (int i=0;i<4;i++) *reinterpret_cast<f32x4*>(&red[wid][d0+i][e0]) = acc[i];
    __syncthreads();
    int de0 = tid * 4;
    const float* rf = &red[0][0][0];
    f32x4 s = *reinterpret_cast<const f32x4*>(rf + de0);
    #pragma unroll
    for (int w=1; w<4; w++) s += *reinterpret_cast<const f32x4*>(rf + w*1024 + de0);
    *reinterpret_cast<f32x4*>(kvpart + ((size_t)bh*16 + chunk)*1024 + de0) = s;
}

// ---------------- reduce partials -> kvT f16 [bh][e][d], scaled 1/HW ----------------
__global__ void k_kvred(const float* __restrict__ kvpart, f16* __restrict__ kvT){
    int gid = blockIdx.x*blockDim.x + threadIdx.x; // 65536
    int bh = gid >> 10, de = gid & 1023;
    int d = de >> 5, e = de & 31;
    float s = 0.f;
    #pragma unroll
    for (int p=0; p<16; p++) s += kvpart[((size_t)bh*16 + p)*1024 + de];
    kvT[((size_t)bh << 10) + (e << 5) + d] = (f16)(s * (1.0f/4096.0f));
}

// ---------------- attn: ret = q @ kvT^T + xb, MFMA ----------------
__global__ __launch_bounds__(256) void k_attn(const f16* __restrict__ qb, const f16* __restrict__ kvT,
                                              const f16* __restrict__ xb, f16* __restrict__ ret){
    const int bh = blockIdx.x, chunk = blockIdx.y;
    const int b = bh >> 3, h = bh & 7;
    const int tid = threadIdx.x, lane = tid & 63, wid = tid >> 6;
    const int lr = lane & 15, kg = lane >> 4;
    const int row0 = chunk*128 + wid*32;

    f32x4 acc[2][2];
    #pragma unroll
    for (int i=0;i<2;i++)
        #pragma unroll
        for (int j=0;j<2;j++) acc[i][j] = (f32x4){0.f,0.f,0.f,0.f};

    f16x8 a[2], bb[2];
    #pragma unroll
    for (int fr=0; fr<2; fr++)
        a[fr] = *reinterpret_cast<const f16x8*>(qb + ((size_t)bh*HW_ + row0 + fr*16 + lr)*HEADC + kg*8);
    #pragma unroll
    for (int fc=0; fc<2; fc++)
        bb[fc] = *reinterpret_cast<const f16x8*>(kvT + ((size_t)bh << 10) + (size_t)(fc*16 + lr)*32 + kg*8);
    #pragma unroll
    for (int fr=0; fr<2; fr++)
        #pragma unroll
        for (int fc=0; fc<2; fc++)
            acc[fr][fc] = __builtin_amdgcn_mfma_f32_16x16x32_f16(a[fr], bb[fc], acc[fr][fc], 0, 0, 0);

    #pragma unroll
    for (int fr=0; fr<2; fr++)
    #pragma unroll
    for (int fc=0; fc<2; fc++)
    #pragma unroll
    for (int r=0; r<4; r++){
        int n = row0 + fr*16 + kg*4 + r;
        int e = fc*16 + lr;
        size_t xi = ((size_t)b*HW_ + n)*MIDC + h*HEADC + e;
        ret[xi] = (f16)(acc[fr][fc][r] + (float)xb[xi]);
    }
}

extern "C" void kernel_launch(void* const* d_in, const int* in_sizes, int n_in,
                              void* d_out, int out_size, void* d_ws, size_t ws_size,
                              hipStream_t stream) {
    const float* x     = (const float*)d_in[0];
    const float* w_qkv = (const float*)d_in[1];
    const float* b_qkv = (const float*)d_in[2];
    const float* kln_g = (const float*)d_in[3];
    const float* kln_b = (const float*)d_in[4];
    const float* vln_g = (const float*)d_in[5];
    const float* vln_b = (const float*)d_in[6];
    const float* w1    = (const float*)d_in[7];
    const float* b1    = (const float*)d_in[8];
    const float* w2    = (const float*)d_in[9];
    const float* b2    = (const float*)d_in[10];
    float* out = (float*)d_out;

    char* ws = (char*)d_ws;
    size_t off = 0;
    auto alloc = [&](size_t bytes) -> void* {
        void* p = ws + off; off += (bytes + 255) & ~255ULL; return p;
    };
    const size_t TOKB = (size_t)NTOK*MIDC*sizeof(f16); // 16.78 MB
    f16* xb    = (f16*)alloc(TOKB);               // preserved (residuals)
    f16* wqkvT = (f16*)alloc(768*256*sizeof(f16));
    f16* w1T   = (f16*)alloc(256*256*sizeof(f16));
    f16* w2T   = (f16*)alloc(256*256*sizeof(f16));
    float* pb  = (float*)alloc(768*sizeof(float));
    f16* qb    = (f16*)alloc(TOKB);
    f16* kb    = (f16*)alloc(TOKB);               // reused as h after k_kv
    f16* vb    = (f16*)alloc(TOKB);               // reused as ret after k_kv
    float* kvpart = (float*)alloc((size_t)64*16*1024*sizeof(float)); // 4 MB
    f16* kvT   = (f16*)alloc((size_t)64*1024*sizeof(f16));
    f16* retb = vb;
    f16* hb   = kb;

    // 1. converts / weight prep
    k_f32_to_f16<<<dim3((NTOK*MIDC)/4/256), 256, 0, stream>>>(x, xb, NTOK*MIDC);
    k_prep<<<dim3((328448+255)/256), 256, 0, stream>>>(w_qkv, w1, w2, b_qkv, wqkvT, w1T, w2T, pb);

    // 2. QKV GEMM + bias + LN(k,v) + coalesced scatter
    k_gemm<0><<<dim3(768/128, NTOK/128), 256, 0, stream>>>(
        xb, wqkvT, pb, kln_g, kln_b, vln_g, vln_b,
        qb, kb, vb, nullptr, nullptr, nullptr);

    // 3. kv partials + reduce (-> kvT, pre-scaled, transposed)
    k_kv<<<dim3(64, HW_/256), 256, 0, stream>>>(kb, vb, kvpart);
    k_kvred<<<dim3(65536/256), 256, 0, stream>>>(kvpart, kvT);

    // 4. attn + residual(xb f16) -> ret f16 (into vb space)
    k_attn<<<dim3(64, HW_/128), 256, 0, stream>>>(qb, kvT, xb, retb);

    // 5. MLP1 (+GELU) -> h (into kb space)
    k_gemm<1><<<dim3(256/128, NTOK/128), 256, 0, stream>>>(
        retb, w1T, b1, nullptr, nullptr, nullptr, nullptr,
        nullptr, nullptr, nullptr, hb, nullptr, nullptr);

    // 6. MLP2 (+bias +resid xb) -> f32 out
    k_gemm<2><<<dim3(256/128, NTOK/128), 256, 0, stream>>>(
        hb, w2T, b2, nullptr, nullptr, nullptr, nullptr,
        nullptr, nullptr, nullptr, nullptr, xb, out);
}